// Round 5
// baseline (780.210 us; speedup 1.0000x reference)
//
#include <hip/hip_runtime.h>
#include <cmath>

typedef short  short8 __attribute__((ext_vector_type(8)));
typedef float  f32x4  __attribute__((ext_vector_type(4)));
typedef unsigned short us8 __attribute__((ext_vector_type(8)));
typedef unsigned short us4 __attribute__((ext_vector_type(4)));

constexpr int kHW = 65536;           // 256*256
constexpr int kP  = 262144;          // 4 * kHW total pixels

__device__ __forceinline__ unsigned short f2bf(float x) {
  unsigned u = __builtin_bit_cast(unsigned, x);
  u += 0x7fffu + ((u >> 16) & 1u);
  return (unsigned short)(u >> 16);
}
__device__ __forceinline__ float bf2f(unsigned short h) {
  unsigned u = ((unsigned)h) << 16;
  return __builtin_bit_cast(float, u);
}
__device__ __forceinline__ void split2(float v, unsigned short& h, unsigned short& l) {
  unsigned short hh = f2bf(v);
  h = hh;
  l = f2bf(v - bf2f(hh));
}

// ---------------- bias table: bias_tab[h][i][j], h<6, i,j<64 ----------------
__global__ void bias_kernel(const float* __restrict__ w1, const float* __restrict__ b1,
                            const float* __restrict__ w2, const float* __restrict__ b2,
                            float* __restrict__ bias_tab) {
  int i = blockIdx.x;
  int j = threadIdx.x;
  float dy = (float)((i >> 3) - (j >> 3));
  float dx = (float)((i & 7) - (j & 7));
  float r0 = copysignf(log1pf(fabsf(dy)), dy);
  float r1 = copysignf(log1pf(fabsf(dx)), dx);
  float acc[6];
#pragma unroll
  for (int h = 0; h < 6; ++h) acc[h] = b2[h];
  for (int t = 0; t < 256; ++t) {
    float hv = fmaf(r0, w1[t], fmaf(r1, w1[256 + t], b1[t]));
    hv = fmaxf(hv, 0.f);
#pragma unroll
    for (int h = 0; h < 6; ++h) acc[h] = fmaf(hv, w2[t * 6 + h], acc[h]);
  }
#pragma unroll
  for (int h = 0; h < 6; ++h) bias_tab[h * 4096 + i * 64 + j] = acc[h];
}

// ---------------- weight prep: fp32 -> bf16 hi/lo planes ---------------------
__global__ void prep_weights(const float* __restrict__ qk_w, const float* __restrict__ v_w,
                             const float* __restrict__ c1w, const float* __restrict__ c2w,
                             const float* __restrict__ pjw,
                             unsigned short* __restrict__ Wqh, unsigned short* __restrict__ Wql,
                             unsigned short* __restrict__ W1h, unsigned short* __restrict__ W1l,
                             unsigned short* __restrict__ W2h, unsigned short* __restrict__ W2l,
                             unsigned short* __restrict__ Wph, unsigned short* __restrict__ Wpl) {
  int i = blockIdx.x * 256 + threadIdx.x;
  if (i < 27648) {
    float v = (i < 18432) ? qk_w[i] : v_w[i - 18432];
    split2(v, Wqh[i], Wql[i]);
  }
  if (i < 82944) {
    int dlt = i / 9216;
    int oc  = (i / 96) % 96;
    int ic  = i % 96;
    int src = (oc * 96 + ic) * 9 + dlt;
    split2(c1w[src], W1h[i], W1l[i]);
    split2(c2w[src], W2h[i], W2l[i]);
  }
  if (i < 9216) split2(pjw[i], Wph[i], Wpl[i]);
}

// ---------------- X: NCHW fp32 -> NHWC bf16 hi/lo ---------------------------
__global__ __launch_bounds__(256) void split_x(const float* __restrict__ X,
                                               unsigned short* __restrict__ Xh,
                                               unsigned short* __restrict__ Xl) {
  __shared__ float tile[96][65];
  int t = threadIdx.x;
  size_t p0 = (size_t)blockIdx.x * 64;
  int b = (int)(p0 >> 16), pix = (int)(p0 & 65535);
  const float* xb = X + (size_t)b * 96 * kHW + pix;
#pragma unroll
  for (int i = 0; i < 24; ++i) {
    int ic = (t >> 6) + i * 4;
    tile[ic][t & 63] = xb[(size_t)ic * kHW + (t & 63)];
  }
  __syncthreads();
  int px = t >> 2;
  size_t outbase = (p0 + px) * 96;
#pragma unroll
  for (int cc = 0; cc < 3; ++cc) {
    int c = (t & 3) + cc * 4;
    us8 h8, l8;
#pragma unroll
    for (int j = 0; j < 8; ++j) {
      unsigned short hh, ll;
      split2(tile[c * 8 + j][px], hh, ll);
      h8[j] = hh; l8[j] = ll;
    }
    *(us8*)(Xh + outbase + c * 8) = h8;
    *(us8*)(Xl + outbase + c * 8) = l8;
  }
}

// ---------------- shared MFMA core: D[MF*16 oc][64 px] ----------------------
// A pointers pre-offset to the oc-block start.
template <int MF, bool BLO>
__device__ __forceinline__ void gemm_core(
    const unsigned short* __restrict__ Wh, const unsigned short* __restrict__ Wl,
    const unsigned short* __restrict__ Xh, const unsigned short* __restrict__ Xl,
    size_t px0, int lane, f32x4 (&acc)[MF][4]) {
  int col = lane & 15, g = lane >> 4;
  const char* aH = (const char*)Wh + (size_t)(col * 96 + g * 8) * 2;
  const char* aL = (const char*)Wl + (size_t)(col * 96 + g * 8) * 2;
  const char* bH = (const char*)Xh + ((px0 + col) * 96 + g * 8) * 2;
  const char* bL = (const char*)Xl + ((px0 + col) * 96 + g * 8) * 2;
#pragma unroll
  for (int ks = 0; ks < 3; ++ks) {
    short8 Ahf[MF], Alf[MF], Bhf[4], Blf[4];
#pragma unroll
    for (int mf = 0; mf < MF; ++mf) {
      Ahf[mf] = *(const short8*)(aH + (size_t)(mf * 16 * 96 + ks * 32) * 2);
      Alf[mf] = *(const short8*)(aL + (size_t)(mf * 16 * 96 + ks * 32) * 2);
    }
#pragma unroll
    for (int nf = 0; nf < 4; ++nf) {
      Bhf[nf] = *(const short8*)(bH + (size_t)(nf * 16 * 96 + ks * 32) * 2);
      if (BLO) Blf[nf] = *(const short8*)(bL + (size_t)(nf * 16 * 96 + ks * 32) * 2);
    }
#pragma unroll
    for (int mf = 0; mf < MF; ++mf)
#pragma unroll
      for (int nf = 0; nf < 4; ++nf) {
        acc[mf][nf] = __builtin_amdgcn_mfma_f32_16x16x32_bf16(Ahf[mf], Bhf[nf], acc[mf][nf], 0, 0, 0);
        if (BLO)
          acc[mf][nf] = __builtin_amdgcn_mfma_f32_16x16x32_bf16(Ahf[mf], Blf[nf], acc[mf][nf], 0, 0, 0);
        acc[mf][nf] = __builtin_amdgcn_mfma_f32_16x16x32_bf16(Alf[mf], Bhf[nf], acc[mf][nf], 0, 0, 0);
      }
  }
}

// ---------------- QKV GEMM: y = (z,och); 48 oc per block --------------------
__global__ __launch_bounds__(256, 4) void qkv_gemm(
    const unsigned short* __restrict__ Wqh, const unsigned short* __restrict__ Wql,
    const unsigned short* __restrict__ Xh, const unsigned short* __restrict__ Xl,
    const float* __restrict__ qk_b, const float* __restrict__ v_b,
    unsigned short* __restrict__ Qp, unsigned short* __restrict__ Kp,
    unsigned short* __restrict__ Vp, unsigned short* __restrict__ Vr) {
  int t = threadIdx.x, wv = t >> 6, lane = t & 63;
  int zo = blockIdx.y, z = zo >> 1, och = zo & 1;
  size_t px0 = (size_t)blockIdx.x * 256 + wv * 64;
  f32x4 acc[3][4];
#pragma unroll
  for (int m = 0; m < 3; ++m)
#pragma unroll
    for (int n = 0; n < 4; ++n) acc[m][n] = (f32x4)0.f;
  gemm_core<3, true>(Wqh + z * 9216 + och * 4608, Wql + z * 9216 + och * 4608,
                     Xh, Xl, px0, lane, acc);
  int col = lane & 15, g = lane >> 4;
  const float* bias = (z == 0) ? qk_b : (z == 1 ? qk_b + 96 : v_b);
  float scale = (z == 0) ? 0.25f : 1.f;
#pragma unroll
  for (int mf = 0; mf < 3; ++mf) {
    int oc0 = och * 48 + mf * 16 + g * 4;
    f32x4 bv;
#pragma unroll
    for (int r = 0; r < 4; ++r) bv[r] = bias[oc0 + r];
#pragma unroll
    for (int nf = 0; nf < 4; ++nf) {
      size_t p = px0 + nf * 16 + col;
      f32x4 v = (acc[mf][nf] + bv) * scale;
      us4 o;
#pragma unroll
      for (int r = 0; r < 4; ++r) o[r] = f2bf(v[r]);
      size_t hoff = ((size_t)(och * 3 + mf) * kP + p) * 16 + g * 4;   // head-planar
      if (z == 0)      *(us4*)(Qp + hoff) = o;
      else if (z == 1) *(us4*)(Kp + hoff) = o;
      else {
        *(us4*)(Vp + hoff) = o;
        *(us4*)(Vr + p * 96 + oc0) = o;
      }
    }
  }
}

// ---------------- attention: reg-resident scores, conflict-free LDS ---------
__global__ __launch_bounds__(256) void attn_kernel(
    const unsigned short* __restrict__ Qp, const unsigned short* __restrict__ Kp,
    const unsigned short* __restrict__ Vp, const float* __restrict__ bias_tab,
    float* __restrict__ out) {
  __shared__ float bs[64 * 65];
  __shared__ float4 kls[4][4][64];   // [wv][d4][j] - write lane-stride 16B, read broadcast
  __shared__ float4 vls[4][4][64];
  int t = threadIdx.x;
  int wv = t >> 6, lane = t & 63;
  int h = blockIdx.y;
  int wid = blockIdx.x * 4 + wv;
  int b = wid >> 10, wy = (wid >> 5) & 31, wx = wid & 31;
  size_t p = ((size_t)b << 16) + (size_t)(wy * 8 + (lane >> 3)) * 256 + wx * 8 + (lane & 7);
  size_t base = ((size_t)h * kP + p) * 16;
  us8 q0 = *(const us8*)(Qp + base), q1 = *(const us8*)(Qp + base + 8);
  us8 k0 = *(const us8*)(Kp + base), k1 = *(const us8*)(Kp + base + 8);
  us8 v0 = *(const us8*)(Vp + base), v1 = *(const us8*)(Vp + base + 8);
  float q[16];
#pragma unroll
  for (int d = 0; d < 8; ++d) {
    q[d]     = bf2f(q0[d]);          // already scaled by 0.25 in qkv
    q[8 + d] = bf2f(q1[d]);
  }
  kls[wv][0][lane] = make_float4(bf2f(k0[0]), bf2f(k0[1]), bf2f(k0[2]), bf2f(k0[3]));
  kls[wv][1][lane] = make_float4(bf2f(k0[4]), bf2f(k0[5]), bf2f(k0[6]), bf2f(k0[7]));
  kls[wv][2][lane] = make_float4(bf2f(k1[0]), bf2f(k1[1]), bf2f(k1[2]), bf2f(k1[3]));
  kls[wv][3][lane] = make_float4(bf2f(k1[4]), bf2f(k1[5]), bf2f(k1[6]), bf2f(k1[7]));
  vls[wv][0][lane] = make_float4(bf2f(v0[0]), bf2f(v0[1]), bf2f(v0[2]), bf2f(v0[3]));
  vls[wv][1][lane] = make_float4(bf2f(v0[4]), bf2f(v0[5]), bf2f(v0[6]), bf2f(v0[7]));
  vls[wv][2][lane] = make_float4(bf2f(v1[0]), bf2f(v1[1]), bf2f(v1[2]), bf2f(v1[3]));
  vls[wv][3][lane] = make_float4(bf2f(v1[4]), bf2f(v1[5]), bf2f(v1[6]), bf2f(v1[7]));
  {
    const float* bp = bias_tab + h * 4096;
#pragma unroll
    for (int r0 = 0; r0 < 16; ++r0) {
      int r = wv * 16 + r0;
      bs[r * 65 + lane] = bp[r * 64 + lane];
    }
  }
  __syncthreads();

  const float* brow = bs + lane * 65;
  float s[64];
#pragma unroll
  for (int j = 0; j < 64; ++j) {
    float kk[16];
    *(float4*)&kk[0]  = kls[wv][0][j];
    *(float4*)&kk[4]  = kls[wv][1][j];
    *(float4*)&kk[8]  = kls[wv][2][j];
    *(float4*)&kk[12] = kls[wv][3][j];
    float dot = brow[j];
#pragma unroll
    for (int d = 0; d < 16; ++d) dot = fmaf(q[d], kk[d], dot);
    s[j] = dot;
  }
  float m = s[0];
#pragma unroll
  for (int j = 1; j < 64; ++j) m = fmaxf(m, s[j]);
  float sum = 0.f;
#pragma unroll
  for (int j = 0; j < 64; ++j) { s[j] = __expf(s[j] - m); sum += s[j]; }
  float r = 1.f / sum;
  float o[16];
#pragma unroll
  for (int d = 0; d < 16; ++d) o[d] = 0.f;
#pragma unroll
  for (int j = 0; j < 64; ++j) {
    float vv[16];
    *(float4*)&vv[0]  = vls[wv][0][j];
    *(float4*)&vv[4]  = vls[wv][1][j];
    *(float4*)&vv[8]  = vls[wv][2][j];
    *(float4*)&vv[12] = vls[wv][3][j];
    float pj = s[j];
#pragma unroll
    for (int d = 0; d < 16; ++d) o[d] = fmaf(pj, vv[d], o[d]);
  }
#pragma unroll
  for (int d = 0; d < 16; ++d) o[d] *= r;
  float* op = out + base;
  *(float4*)(op)      = *(float4*)&o[0];
  *(float4*)(op + 4)  = *(float4*)&o[4];
  *(float4*)(op + 8)  = *(float4*)&o[8];
  *(float4*)(op + 12) = *(float4*)&o[12];
}

// ---------------- 3x3 reflect conv: 48 oc per block, 9 shifted GEMMs --------
template <int MODE>
__global__ __launch_bounds__(256, 4) void conv_gemm(
    const unsigned short* __restrict__ Wh, const unsigned short* __restrict__ Wl,
    const unsigned short* __restrict__ B_, const float* __restrict__ bias,
    const float* __restrict__ attn, unsigned short* __restrict__ O_) {
  int t = threadIdx.x, wv = t >> 6, lane = t & 63;
  int col = lane & 15, g = lane >> 4;
  int bid = blockIdx.x;
  int g8 = (bid & 7) * 256 + (bid >> 3);   // XCD-chunked over 2048 blocks
  int och = g8 & 1;
  int ry = g8 >> 1;                        // 0..1023; ry contiguous per XCD
  int b = ry >> 8, y = ry & 255;
  int x0 = wv * 64;
  f32x4 acc[3][4];
#pragma unroll
  for (int m = 0; m < 3; ++m)
#pragma unroll
    for (int n = 0; n < 4; ++n) acc[m][n] = (f32x4)0.f;

  unsigned gxo[4][3];
#pragma unroll
  for (int nf = 0; nf < 4; ++nf)
#pragma unroll
    for (int dx = 0; dx < 3; ++dx) {
      int xx = x0 + nf * 16 + col + dx - 1;
      xx = xx < 0 ? 1 : (xx > 255 ? 254 : xx);
      gxo[nf][dx] = (unsigned)xx * 192u + (unsigned)g * 16u;
    }
  size_t bbase = (size_t)b * kHW * 192;

#pragma unroll 1
  for (int dy = 0; dy < 3; ++dy) {
    int yy = y + dy - 1;
    yy = yy < 0 ? 1 : (yy > 255 ? 254 : yy);
    const char* bh = (const char*)B_ + bbase + (size_t)yy * 256 * 192;
#pragma unroll
    for (int dx = 0; dx < 3; ++dx) {
      const char* ah = (const char*)Wh + ((size_t)(dy * 3 + dx) * 9216 + och * 4608 + col * 96 + g * 8) * 2;
      const char* al = (const char*)Wl + ((size_t)(dy * 3 + dx) * 9216 + och * 4608 + col * 96 + g * 8) * 2;
#pragma unroll
      for (int ks = 0; ks < 3; ++ks) {
        short8 Ahf[3], Alf[3], Bhf[4];
#pragma unroll
        for (int mf = 0; mf < 3; ++mf) {
          Ahf[mf] = *(const short8*)(ah + (size_t)(mf * 16 * 96 + ks * 32) * 2);
          Alf[mf] = *(const short8*)(al + (size_t)(mf * 16 * 96 + ks * 32) * 2);
        }
#pragma unroll
        for (int nf = 0; nf < 4; ++nf)
          Bhf[nf] = *(const short8*)(bh + gxo[nf][dx] + ks * 64);
#pragma unroll
        for (int mf = 0; mf < 3; ++mf)
#pragma unroll
          for (int nf = 0; nf < 4; ++nf) {
            acc[mf][nf] = __builtin_amdgcn_mfma_f32_16x16x32_bf16(Ahf[mf], Bhf[nf], acc[mf][nf], 0, 0, 0);
            acc[mf][nf] = __builtin_amdgcn_mfma_f32_16x16x32_bf16(Alf[mf], Bhf[nf], acc[mf][nf], 0, 0, 0);
          }
      }
    }
  }

  size_t prow = (size_t)b * kHW + (size_t)y * 256;
#pragma unroll
  for (int mf = 0; mf < 3; ++mf) {
    int oc0 = och * 48 + mf * 16 + g * 4;
    f32x4 bv;
#pragma unroll
    for (int r = 0; r < 4; ++r) bv[r] = bias[oc0 + r];
#pragma unroll
    for (int nf = 0; nf < 4; ++nf) {
      size_t p = prow + x0 + nf * 16 + col;
      f32x4 v = acc[mf][nf] + bv;
      if (MODE == 0) {
#pragma unroll
        for (int r = 0; r < 4; ++r) v[r] = fmaxf(v[r], 0.f);
      } else {
        float4 a = *(const float4*)(attn + ((size_t)(och * 3 + mf) * kP + p) * 16 + g * 4);
        v[0] += a.x; v[1] += a.y; v[2] += a.z; v[3] += a.w;
      }
      us4 o;
#pragma unroll
      for (int r = 0; r < 4; ++r) o[r] = f2bf(v[r]);
      *(us4*)(O_ + p * 96 + oc0) = o;
    }
  }
}

// ---------------- final projection -> d_out NCHW fp32 ------------------------
__global__ __launch_bounds__(256, 4) void proj_gemm(
    const unsigned short* __restrict__ Wph, const unsigned short* __restrict__ Wpl,
    const unsigned short* __restrict__ S_, const float* __restrict__ bias,
    float* __restrict__ out) {
  int t = threadIdx.x, wv = t >> 6, lane = t & 63;
  int och = blockIdx.y;
  size_t px0 = (size_t)blockIdx.x * 256 + wv * 64;
  f32x4 acc[3][4];
#pragma unroll
  for (int m = 0; m < 3; ++m)
#pragma unroll
    for (int n = 0; n < 4; ++n) acc[m][n] = (f32x4)0.f;
  gemm_core<3, false>(Wph + och * 4608, Wpl + och * 4608, S_, S_, px0, lane, acc);
  int col = lane & 15, g = lane >> 4;
#pragma unroll
  for (int mf = 0; mf < 3; ++mf) {
    int oc0 = och * 48 + mf * 16 + g * 4;
#pragma unroll
    for (int nf = 0; nf < 4; ++nf) {
      size_t p = px0 + nf * 16 + col;
      size_t bb = p >> 16, pix = p & 65535;
      f32x4 v = acc[mf][nf];
#pragma unroll
      for (int r = 0; r < 4; ++r)
        out[(bb * 96 + oc0 + r) * (size_t)kHW + pix] = v[r] + bias[oc0 + r];
    }
  }
}

extern "C" void kernel_launch(void* const* d_in, const int* in_sizes, int n_in,
                              void* d_out, int out_size, void* d_ws, size_t ws_size,
                              hipStream_t stream) {
  const float* X       = (const float*)d_in[0];
  const float* V_w     = (const float*)d_in[1];
  const float* V_b     = (const float*)d_in[2];
  const float* QK_w    = (const float*)d_in[3];
  const float* QK_b    = (const float*)d_in[4];
  const float* meta_w1 = (const float*)d_in[5];
  const float* meta_b1 = (const float*)d_in[6];
  const float* meta_w2 = (const float*)d_in[7];
  const float* meta_b2 = (const float*)d_in[8];
  const float* conv1_w = (const float*)d_in[9];
  const float* conv1_b = (const float*)d_in[10];
  const float* conv2_w = (const float*)d_in[11];
  const float* conv2_b = (const float*)d_in[12];
  const float* proj_w  = (const float*)d_in[13];
  const float* proj_b  = (const float*)d_in[14];
  float* out = (float*)d_out;

  char* w = (char*)d_ws;
  const size_t PLANE = (size_t)kP * 96 * 2;      // 50,331,648 B
  unsigned short* Xh = (unsigned short*)(w + 0 * PLANE);
  unsigned short* Xl = (unsigned short*)(w + 1 * PLANE);
  unsigned short* Qp = (unsigned short*)(w + 2 * PLANE);
  unsigned short* Kp = (unsigned short*)(w + 3 * PLANE);
  unsigned short* Vp = (unsigned short*)(w + 4 * PLANE);
  unsigned short* Vr = (unsigned short*)(w + 5 * PLANE);
  float* bias_tab    = (float*)(w + 6 * PLANE);
  unsigned short* Wqh = (unsigned short*)(w + 6 * PLANE + 98304);
  unsigned short* Wql = Wqh + 27648;
  unsigned short* W1h = Wql + 27648;
  unsigned short* W1l = W1h + 82944;
  unsigned short* W2h = W1l + 82944;
  unsigned short* W2l = W2h + 82944;
  unsigned short* Wph = W2l + 82944;
  unsigned short* Wpl = Wph + 9216;
  // stream-ordered aliases
  unsigned short* T1r = Xh;            // X dead after qkv_gemm
  unsigned short* S2r = Qp;            // Q dead after attn
  float* attnF = out;                  // d_out as head-planar f32 scratch; proj overwrites

  bias_kernel<<<dim3(64), dim3(64), 0, stream>>>(meta_w1, meta_b1, meta_w2, meta_b2, bias_tab);
  prep_weights<<<dim3(324), dim3(256), 0, stream>>>(QK_w, V_w, conv1_w, conv2_w, proj_w,
                                                    Wqh, Wql, W1h, W1l, W2h, W2l, Wph, Wpl);
  split_x<<<dim3(4096), dim3(256), 0, stream>>>(X, Xh, Xl);
  qkv_gemm<<<dim3(1024, 6), dim3(256), 0, stream>>>(Wqh, Wql, Xh, Xl, QK_b, V_b, Qp, Kp, Vp, Vr);
  attn_kernel<<<dim3(1024, 6), dim3(256), 0, stream>>>(Qp, Kp, Vp, bias_tab, attnF);
  conv_gemm<0><<<dim3(2048), dim3(256), 0, stream>>>(W1h, W1l, Vr, conv1_b, nullptr, T1r);
  conv_gemm<1><<<dim3(2048), dim3(256), 0, stream>>>(W2h, W2l, T1r, conv2_b, attnF, S2r);
  proj_gemm<<<dim3(1024, 2), dim3(256), 0, stream>>>(Wph, Wpl, S2r, proj_b, out);
}

// Round 6
// 630.423 us; speedup vs baseline: 1.2376x; 1.2376x over previous
//
#include <hip/hip_runtime.h>
#include <cmath>

typedef short  short8 __attribute__((ext_vector_type(8)));
typedef float  f32x4  __attribute__((ext_vector_type(4)));
typedef unsigned short us8 __attribute__((ext_vector_type(8)));
typedef unsigned short us4 __attribute__((ext_vector_type(4)));

constexpr int kHW = 65536;           // 256*256
constexpr int kP  = 262144;          // 4 * kHW total pixels

__device__ __forceinline__ unsigned short f2bf(float x) {
  unsigned u = __builtin_bit_cast(unsigned, x);
  u += 0x7fffu + ((u >> 16) & 1u);
  return (unsigned short)(u >> 16);
}
__device__ __forceinline__ float bf2f(unsigned short h) {
  unsigned u = ((unsigned)h) << 16;
  return __builtin_bit_cast(float, u);
}
__device__ __forceinline__ void split2(float v, unsigned short& h, unsigned short& l) {
  unsigned short hh = f2bf(v);
  h = hh;
  l = f2bf(v - bf2f(hh));
}

// ---------------- bias table: bias_tab[h][i][j], h<6, i,j<64 ----------------
__global__ void bias_kernel(const float* __restrict__ w1, const float* __restrict__ b1,
                            const float* __restrict__ w2, const float* __restrict__ b2,
                            float* __restrict__ bias_tab) {
  int i = blockIdx.x;
  int j = threadIdx.x;
  float dy = (float)((i >> 3) - (j >> 3));
  float dx = (float)((i & 7) - (j & 7));
  float r0 = copysignf(log1pf(fabsf(dy)), dy);
  float r1 = copysignf(log1pf(fabsf(dx)), dx);
  float acc[6];
#pragma unroll
  for (int h = 0; h < 6; ++h) acc[h] = b2[h];
  for (int t = 0; t < 256; ++t) {
    float hv = fmaf(r0, w1[t], fmaf(r1, w1[256 + t], b1[t]));
    hv = fmaxf(hv, 0.f);
#pragma unroll
    for (int h = 0; h < 6; ++h) acc[h] = fmaf(hv, w2[t * 6 + h], acc[h]);
  }
#pragma unroll
  for (int h = 0; h < 6; ++h) bias_tab[h * 4096 + i * 64 + j] = acc[h];
}

// ---------------- weight prep: fp32 -> bf16 hi/lo planes ---------------------
__global__ void prep_weights(const float* __restrict__ qk_w, const float* __restrict__ v_w,
                             const float* __restrict__ c1w, const float* __restrict__ c2w,
                             const float* __restrict__ pjw,
                             unsigned short* __restrict__ Wqh, unsigned short* __restrict__ Wql,
                             unsigned short* __restrict__ W1h, unsigned short* __restrict__ W1l,
                             unsigned short* __restrict__ W2h, unsigned short* __restrict__ W2l,
                             unsigned short* __restrict__ Wph, unsigned short* __restrict__ Wpl) {
  int i = blockIdx.x * 256 + threadIdx.x;
  if (i < 27648) {
    float v = (i < 18432) ? qk_w[i] : v_w[i - 18432];
    split2(v, Wqh[i], Wql[i]);
  }
  if (i < 82944) {
    int dlt = i / 9216;
    int oc  = (i / 96) % 96;
    int ic  = i % 96;
    int src = (oc * 96 + ic) * 9 + dlt;
    split2(c1w[src], W1h[i], W1l[i]);
    split2(c2w[src], W2h[i], W2l[i]);
  }
  if (i < 9216) split2(pjw[i], Wph[i], Wpl[i]);
}

// ---------------- X: NCHW fp32 -> NHWC bf16 hi/lo ---------------------------
__global__ __launch_bounds__(256) void split_x(const float* __restrict__ X,
                                               unsigned short* __restrict__ Xh,
                                               unsigned short* __restrict__ Xl) {
  __shared__ float tile[96][65];
  int t = threadIdx.x;
  size_t p0 = (size_t)blockIdx.x * 64;
  int b = (int)(p0 >> 16), pix = (int)(p0 & 65535);
  const float* xb = X + (size_t)b * 96 * kHW + pix;
#pragma unroll
  for (int i = 0; i < 24; ++i) {
    int ic = (t >> 6) + i * 4;
    tile[ic][t & 63] = xb[(size_t)ic * kHW + (t & 63)];
  }
  __syncthreads();
  int px = t >> 2;
  size_t outbase = (p0 + px) * 96;
#pragma unroll
  for (int cc = 0; cc < 3; ++cc) {
    int c = (t & 3) + cc * 4;
    us8 h8, l8;
#pragma unroll
    for (int j = 0; j < 8; ++j) {
      unsigned short hh, ll;
      split2(tile[c * 8 + j][px], hh, ll);
      h8[j] = hh; l8[j] = ll;
    }
    *(us8*)(Xh + outbase + c * 8) = h8;
    *(us8*)(Xl + outbase + c * 8) = l8;
  }
}

// ---------------- shared MFMA core (96 oc): D[96][64 px] --------------------
template <bool BLO>
__device__ __forceinline__ void gemm_core6(
    const unsigned short* __restrict__ Wh, const unsigned short* __restrict__ Wl,
    const unsigned short* __restrict__ Xh, const unsigned short* __restrict__ Xl,
    size_t px0, int lane, f32x4 (&acc)[6][4]) {
  int col = lane & 15, g = lane >> 4;
  const char* aH = (const char*)Wh + (size_t)(col * 96 + g * 8) * 2;
  const char* aL = (const char*)Wl + (size_t)(col * 96 + g * 8) * 2;
  const char* bH = (const char*)Xh + ((px0 + col) * 96 + g * 8) * 2;
  const char* bL = (const char*)Xl + ((px0 + col) * 96 + g * 8) * 2;
#pragma unroll
  for (int ks = 0; ks < 3; ++ks) {
    short8 Ahf[6], Alf[6], Bhf[4], Blf[4];
#pragma unroll
    for (int mf = 0; mf < 6; ++mf) {
      Ahf[mf] = *(const short8*)(aH + (size_t)(mf * 16 * 96 + ks * 32) * 2);
      Alf[mf] = *(const short8*)(aL + (size_t)(mf * 16 * 96 + ks * 32) * 2);
    }
#pragma unroll
    for (int nf = 0; nf < 4; ++nf) {
      Bhf[nf] = *(const short8*)(bH + (size_t)(nf * 16 * 96 + ks * 32) * 2);
      if (BLO) Blf[nf] = *(const short8*)(bL + (size_t)(nf * 16 * 96 + ks * 32) * 2);
    }
#pragma unroll
    for (int mf = 0; mf < 6; ++mf)
#pragma unroll
      for (int nf = 0; nf < 4; ++nf) {
        acc[mf][nf] = __builtin_amdgcn_mfma_f32_16x16x32_bf16(Ahf[mf], Bhf[nf], acc[mf][nf], 0, 0, 0);
        if (BLO)
          acc[mf][nf] = __builtin_amdgcn_mfma_f32_16x16x32_bf16(Ahf[mf], Blf[nf], acc[mf][nf], 0, 0, 0);
        acc[mf][nf] = __builtin_amdgcn_mfma_f32_16x16x32_bf16(Alf[mf], Bhf[nf], acc[mf][nf], 0, 0, 0);
      }
  }
}

// ---------------- QKV GEMM: z=0 Q*0.25, z=1 K, z=2 V ------------------------
__global__ __launch_bounds__(256, 2) void qkv_gemm(
    const unsigned short* __restrict__ Wqh, const unsigned short* __restrict__ Wql,
    const unsigned short* __restrict__ Xh, const unsigned short* __restrict__ Xl,
    const float* __restrict__ qk_b, const float* __restrict__ v_b,
    unsigned short* __restrict__ Qp, unsigned short* __restrict__ Kp,
    unsigned short* __restrict__ Vp, unsigned short* __restrict__ Vr) {
  int t = threadIdx.x, wv = t >> 6, lane = t & 63;
  int z = blockIdx.y;
  size_t px0 = (size_t)blockIdx.x * 256 + wv * 64;
  f32x4 acc[6][4];
#pragma unroll
  for (int m = 0; m < 6; ++m)
#pragma unroll
    for (int n = 0; n < 4; ++n) acc[m][n] = (f32x4)0.f;
  gemm_core6<true>(Wqh + z * 9216, Wql + z * 9216, Xh, Xl, px0, lane, acc);
  int col = lane & 15, g = lane >> 4;
  const float* bias = (z == 0) ? qk_b : (z == 1 ? qk_b + 96 : v_b);
  float scale = (z == 0) ? 0.25f : 1.f;
#pragma unroll
  for (int mf = 0; mf < 6; ++mf) {
    int oc0 = mf * 16 + g * 4;
    f32x4 bv;
#pragma unroll
    for (int r = 0; r < 4; ++r) bv[r] = bias[oc0 + r];
#pragma unroll
    for (int nf = 0; nf < 4; ++nf) {
      size_t p = px0 + nf * 16 + col;
      f32x4 v = (acc[mf][nf] + bv) * scale;
      us4 o;
#pragma unroll
      for (int r = 0; r < 4; ++r) o[r] = f2bf(v[r]);
      size_t hoff = ((size_t)mf * kP + p) * 16 + g * 4;   // head = mf
      if (z == 0)      *(us4*)(Qp + hoff) = o;
      else if (z == 1) *(us4*)(Kp + hoff) = o;
      else {
        *(us4*)(Vp + hoff) = o;
        *(us4*)(Vr + p * 96 + oc0) = o;
      }
    }
  }
}

// ---------------- attention: reg-resident scores, conflict-free LDS ---------
__global__ __launch_bounds__(256) void attn_kernel(
    const unsigned short* __restrict__ Qp, const unsigned short* __restrict__ Kp,
    const unsigned short* __restrict__ Vp, const float* __restrict__ bias_tab,
    float* __restrict__ out) {
  __shared__ float bs[64 * 65];
  __shared__ float4 kls[4][4][64];
  __shared__ float4 vls[4][4][64];
  int t = threadIdx.x;
  int wv = t >> 6, lane = t & 63;
  int h = blockIdx.y;
  int wid = blockIdx.x * 4 + wv;
  int b = wid >> 10, wy = (wid >> 5) & 31, wx = wid & 31;
  size_t p = ((size_t)b << 16) + (size_t)(wy * 8 + (lane >> 3)) * 256 + wx * 8 + (lane & 7);
  size_t base = ((size_t)h * kP + p) * 16;
  us8 q0 = *(const us8*)(Qp + base), q1 = *(const us8*)(Qp + base + 8);
  us8 k0 = *(const us8*)(Kp + base), k1 = *(const us8*)(Kp + base + 8);
  us8 v0 = *(const us8*)(Vp + base), v1 = *(const us8*)(Vp + base + 8);
  float q[16];
#pragma unroll
  for (int d = 0; d < 8; ++d) {
    q[d]     = bf2f(q0[d]);
    q[8 + d] = bf2f(q1[d]);
  }
  kls[wv][0][lane] = make_float4(bf2f(k0[0]), bf2f(k0[1]), bf2f(k0[2]), bf2f(k0[3]));
  kls[wv][1][lane] = make_float4(bf2f(k0[4]), bf2f(k0[5]), bf2f(k0[6]), bf2f(k0[7]));
  kls[wv][2][lane] = make_float4(bf2f(k1[0]), bf2f(k1[1]), bf2f(k1[2]), bf2f(k1[3]));
  kls[wv][3][lane] = make_float4(bf2f(k1[4]), bf2f(k1[5]), bf2f(k1[6]), bf2f(k1[7]));
  vls[wv][0][lane] = make_float4(bf2f(v0[0]), bf2f(v0[1]), bf2f(v0[2]), bf2f(v0[3]));
  vls[wv][1][lane] = make_float4(bf2f(v0[4]), bf2f(v0[5]), bf2f(v0[6]), bf2f(v0[7]));
  vls[wv][2][lane] = make_float4(bf2f(v1[0]), bf2f(v1[1]), bf2f(v1[2]), bf2f(v1[3]));
  vls[wv][3][lane] = make_float4(bf2f(v1[4]), bf2f(v1[5]), bf2f(v1[6]), bf2f(v1[7]));
  {
    const float* bp = bias_tab + h * 4096;
#pragma unroll
    for (int r0 = 0; r0 < 16; ++r0) {
      int r = wv * 16 + r0;
      bs[r * 65 + lane] = bp[r * 64 + lane];
    }
  }
  __syncthreads();

  const float* brow = bs + lane * 65;
  float s[64];
#pragma unroll
  for (int j = 0; j < 64; ++j) {
    float kk[16];
    *(float4*)&kk[0]  = kls[wv][0][j];
    *(float4*)&kk[4]  = kls[wv][1][j];
    *(float4*)&kk[8]  = kls[wv][2][j];
    *(float4*)&kk[12] = kls[wv][3][j];
    float dot = brow[j];
#pragma unroll
    for (int d = 0; d < 16; ++d) dot = fmaf(q[d], kk[d], dot);
    s[j] = dot;
  }
  float m = s[0];
#pragma unroll
  for (int j = 1; j < 64; ++j) m = fmaxf(m, s[j]);
  float sum = 0.f;
#pragma unroll
  for (int j = 0; j < 64; ++j) { s[j] = __expf(s[j] - m); sum += s[j]; }
  float r = 1.f / sum;
  float o[16];
#pragma unroll
  for (int d = 0; d < 16; ++d) o[d] = 0.f;
#pragma unroll
  for (int j = 0; j < 64; ++j) {
    float vv[16];
    *(float4*)&vv[0]  = vls[wv][0][j];
    *(float4*)&vv[4]  = vls[wv][1][j];
    *(float4*)&vv[8]  = vls[wv][2][j];
    *(float4*)&vv[12] = vls[wv][3][j];
    float pj = s[j];
#pragma unroll
    for (int d = 0; d < 16; ++d) o[d] = fmaf(pj, vv[d], o[d]);
  }
#pragma unroll
  for (int d = 0; d < 16; ++d) o[d] *= r;
  float* op = out + base;
  *(float4*)(op)      = *(float4*)&o[0];
  *(float4*)(op + 4)  = *(float4*)&o[4];
  *(float4*)(op + 8)  = *(float4*)&o[8];
  *(float4*)(op + 12) = *(float4*)&o[12];
}

// ---------------- conv: LDS-staged B, rolling row double-buffer -------------
// block = 96 oc x 128 px of one row; 4 waves = 2 och x 2 xq; acc[3][4]/wave.
// LDS: 2 x 130 px x 192 B (bf16 ch), XOR-swizzled g-chunk; 49.9 KB total.
constexpr int kRowB = 130 * 192;     // 24960 bytes per row buffer
constexpr int kChunks = 130 * 12;    // 1560 16-B chunks per row

__device__ __forceinline__ void stage_issue(const unsigned short* __restrict__ row,
                                            int x0, int t, us8 (&v)[7]) {
#pragma unroll
  for (int i = 0; i < 7; ++i) {
    int idx = i * 256 + t;
    if (idx < kChunks) {
      int pp = idx / 12, cb = idx % 12;
      int xx = x0 - 1 + pp;
      xx = xx < 0 ? 1 : (xx > 255 ? 254 : xx);
      v[i] = *(const us8*)(row + (size_t)xx * 96 + cb * 8);
    }
  }
}
__device__ __forceinline__ void stage_write(char* __restrict__ lds, int t, const us8 (&v)[7]) {
#pragma unroll
  for (int i = 0; i < 7; ++i) {
    int idx = i * 256 + t;
    if (idx < kChunks) {
      int pp = idx / 12, cb = idx % 12;
      int gq = cb & 3, ks = cb >> 2;
      int dst = pp * 192 + ks * 64 + ((gq ^ (pp & 3)) << 4);
      *(us8*)(lds + dst) = v[i];
    }
  }
}

__device__ __forceinline__ void conv_dy(
    const char* __restrict__ lds,
    const unsigned short* __restrict__ Wh, const unsigned short* __restrict__ Wl,
    int tap0, int och, int xq, int col, int g, f32x4 (&acc)[3][4]) {
#pragma unroll
  for (int dx = 0; dx < 3; ++dx) {
    const char* ah = (const char*)Wh + ((size_t)(tap0 + dx) * 9216 + och * 4608 + col * 96 + g * 8) * 2;
    const char* al = (const char*)Wl + ((size_t)(tap0 + dx) * 9216 + och * 4608 + col * 96 + g * 8) * 2;
    int g2 = ((g ^ ((col + dx) & 3)) << 4);
    int ppb = xq * 64 + col + dx;
#pragma unroll
    for (int ks = 0; ks < 3; ++ks) {
      short8 Ah[3], Al[3], Bf[4];
#pragma unroll
      for (int mf = 0; mf < 3; ++mf) {
        Ah[mf] = *(const short8*)(ah + (size_t)(mf * 16 * 96 + ks * 32) * 2);
        Al[mf] = *(const short8*)(al + (size_t)(mf * 16 * 96 + ks * 32) * 2);
      }
#pragma unroll
      for (int nf = 0; nf < 4; ++nf)
        Bf[nf] = *(const short8*)(lds + (ppb + nf * 16) * 192 + ks * 64 + g2);
#pragma unroll
      for (int mf = 0; mf < 3; ++mf)
#pragma unroll
        for (int nf = 0; nf < 4; ++nf) {
          acc[mf][nf] = __builtin_amdgcn_mfma_f32_16x16x32_bf16(Ah[mf], Bf[nf], acc[mf][nf], 0, 0, 0);
          acc[mf][nf] = __builtin_amdgcn_mfma_f32_16x16x32_bf16(Al[mf], Bf[nf], acc[mf][nf], 0, 0, 0);
        }
    }
  }
}

template <int MODE>
__global__ __launch_bounds__(256, 3) void conv_lds(
    const unsigned short* __restrict__ Wh, const unsigned short* __restrict__ Wl,
    const unsigned short* __restrict__ B_, const float* __restrict__ bias,
    const float* __restrict__ attn, unsigned short* __restrict__ O_) {
  __shared__ char lds[2][kRowB];
  int t = threadIdx.x, wv = t >> 6, lane = t & 63;
  int col = lane & 15, g = lane >> 4;
  int och = wv >> 1, xq = wv & 1;
  int bid = blockIdx.x;
  int g8 = (bid & 7) * 256 + (bid >> 3);   // XCD-chunked: consecutive rows per XCD
  int xh = g8 & 1;
  int ry = g8 >> 1;                        // 0..1023
  int b = ry >> 8, y = ry & 255;
  int x0 = xh * 128;

  int ym = (y == 0) ? 1 : y - 1;
  int yp = (y == 255) ? 254 : y + 1;
  const unsigned short* rowm = B_ + ((size_t)b * kHW + (size_t)ym * 256) * 96;
  const unsigned short* row0 = B_ + ((size_t)b * kHW + (size_t)y  * 256) * 96;
  const unsigned short* rowp = B_ + ((size_t)b * kHW + (size_t)yp * 256) * 96;

  f32x4 acc[3][4];
#pragma unroll
  for (int m = 0; m < 3; ++m)
#pragma unroll
    for (int n = 0; n < 4; ++n) acc[m][n] = (f32x4)0.f;

  us8 stg[7];
  // prologue: stage row y-1 into buf0
  stage_issue(rowm, x0, t, stg);
  stage_write(lds[0], t, stg);
  __syncthreads();

  // dy=0 on buf0 while staging row y into buf1
  stage_issue(row0, x0, t, stg);
  conv_dy(lds[0], Wh, Wl, 0, och, xq, col, g, acc);
  stage_write(lds[1], t, stg);
  __syncthreads();

  // dy=1 on buf1 while staging row y+1 into buf0
  stage_issue(rowp, x0, t, stg);
  conv_dy(lds[1], Wh, Wl, 3, och, xq, col, g, acc);
  stage_write(lds[0], t, stg);
  __syncthreads();

  // dy=2 on buf0
  conv_dy(lds[0], Wh, Wl, 6, och, xq, col, g, acc);

  size_t prow = (size_t)b * kHW + (size_t)y * 256;
#pragma unroll
  for (int mf = 0; mf < 3; ++mf) {
    int oc0 = och * 48 + mf * 16 + g * 4;
    f32x4 bv;
#pragma unroll
    for (int r = 0; r < 4; ++r) bv[r] = bias[oc0 + r];
#pragma unroll
    for (int nf = 0; nf < 4; ++nf) {
      size_t p = prow + x0 + xq * 64 + nf * 16 + col;
      f32x4 v = acc[mf][nf] + bv;
      if (MODE == 0) {
#pragma unroll
        for (int r = 0; r < 4; ++r) v[r] = fmaxf(v[r], 0.f);
      } else {
        float4 a = *(const float4*)(attn + ((size_t)(och * 3 + mf) * kP + p) * 16 + g * 4);
        v[0] += a.x; v[1] += a.y; v[2] += a.z; v[3] += a.w;
      }
      us4 o;
#pragma unroll
      for (int r = 0; r < 4; ++r) o[r] = f2bf(v[r]);
      *(us4*)(O_ + p * 96 + oc0) = o;
    }
  }
}

// ---------------- final projection -> d_out NCHW fp32 ------------------------
__global__ __launch_bounds__(256, 2) void proj_gemm(
    const unsigned short* __restrict__ Wph, const unsigned short* __restrict__ Wpl,
    const unsigned short* __restrict__ S_, const float* __restrict__ bias,
    float* __restrict__ out) {
  int t = threadIdx.x, wv = t >> 6, lane = t & 63;
  size_t px0 = (size_t)blockIdx.x * 256 + wv * 64;
  f32x4 acc[6][4];
#pragma unroll
  for (int m = 0; m < 6; ++m)
#pragma unroll
    for (int n = 0; n < 4; ++n) acc[m][n] = (f32x4)0.f;
  gemm_core6<false>(Wph, Wpl, S_, S_, px0, lane, acc);
  int col = lane & 15, g = lane >> 4;
#pragma unroll
  for (int mf = 0; mf < 6; ++mf) {
    int oc0 = mf * 16 + g * 4;
#pragma unroll
    for (int nf = 0; nf < 4; ++nf) {
      size_t p = px0 + nf * 16 + col;
      size_t bb = p >> 16, pix = p & 65535;
      f32x4 v = acc[mf][nf];
#pragma unroll
      for (int r = 0; r < 4; ++r)
        out[(bb * 96 + oc0 + r) * (size_t)kHW + pix] = v[r] + bias[oc0 + r];
    }
  }
}

extern "C" void kernel_launch(void* const* d_in, const int* in_sizes, int n_in,
                              void* d_out, int out_size, void* d_ws, size_t ws_size,
                              hipStream_t stream) {
  const float* X       = (const float*)d_in[0];
  const float* V_w     = (const float*)d_in[1];
  const float* V_b     = (const float*)d_in[2];
  const float* QK_w    = (const float*)d_in[3];
  const float* QK_b    = (const float*)d_in[4];
  const float* meta_w1 = (const float*)d_in[5];
  const float* meta_b1 = (const float*)d_in[6];
  const float* meta_w2 = (const float*)d_in[7];
  const float* meta_b2 = (const float*)d_in[8];
  const float* conv1_w = (const float*)d_in[9];
  const float* conv1_b = (const float*)d_in[10];
  const float* conv2_w = (const float*)d_in[11];
  const float* conv2_b = (const float*)d_in[12];
  const float* proj_w  = (const float*)d_in[13];
  const float* proj_b  = (const float*)d_in[14];
  float* out = (float*)d_out;

  char* w = (char*)d_ws;
  const size_t PLANE = (size_t)kP * 96 * 2;      // 50,331,648 B
  unsigned short* Xh = (unsigned short*)(w + 0 * PLANE);
  unsigned short* Xl = (unsigned short*)(w + 1 * PLANE);
  unsigned short* Qp = (unsigned short*)(w + 2 * PLANE);
  unsigned short* Kp = (unsigned short*)(w + 3 * PLANE);
  unsigned short* Vp = (unsigned short*)(w + 4 * PLANE);
  unsigned short* Vr = (unsigned short*)(w + 5 * PLANE);
  float* bias_tab    = (float*)(w + 6 * PLANE);
  unsigned short* Wqh = (unsigned short*)(w + 6 * PLANE + 98304);
  unsigned short* Wql = Wqh + 27648;
  unsigned short* W1h = Wql + 27648;
  unsigned short* W1l = W1h + 82944;
  unsigned short* W2h = W1l + 82944;
  unsigned short* W2l = W2h + 82944;
  unsigned short* Wph = W2l + 82944;
  unsigned short* Wpl = Wph + 9216;
  // stream-ordered aliases
  unsigned short* T1r = Xh;            // X dead after qkv_gemm
  unsigned short* S2r = Qp;            // Q dead after attn
  float* attnF = out;                  // d_out as head-planar f32 scratch; proj overwrites

  bias_kernel<<<dim3(64), dim3(64), 0, stream>>>(meta_w1, meta_b1, meta_w2, meta_b2, bias_tab);
  prep_weights<<<dim3(324), dim3(256), 0, stream>>>(QK_w, V_w, conv1_w, conv2_w, proj_w,
                                                    Wqh, Wql, W1h, W1l, W2h, W2l, Wph, Wpl);
  split_x<<<dim3(4096), dim3(256), 0, stream>>>(X, Xh, Xl);
  qkv_gemm<<<dim3(1024, 3), dim3(256), 0, stream>>>(Wqh, Wql, Xh, Xl, QK_b, V_b, Qp, Kp, Vp, Vr);
  attn_kernel<<<dim3(1024, 6), dim3(256), 0, stream>>>(Qp, Kp, Vp, bias_tab, attnF);
  conv_lds<0><<<dim3(2048), dim3(256), 0, stream>>>(W1h, W1l, Vr, conv1_b, nullptr, T1r);
  conv_lds<1><<<dim3(2048), dim3(256), 0, stream>>>(W2h, W2l, T1r, conv2_b, attnF, S2r);
  proj_gemm<<<dim3(1024), dim3(256), 0, stream>>>(Wph, Wpl, S2r, proj_b, out);
}

// Round 7
// 566.023 us; speedup vs baseline: 1.3784x; 1.1138x over previous
//
#include <hip/hip_runtime.h>
#include <cmath>

typedef short  short8 __attribute__((ext_vector_type(8)));
typedef float  f32x4  __attribute__((ext_vector_type(4)));
typedef unsigned short us8 __attribute__((ext_vector_type(8)));
typedef unsigned short us4 __attribute__((ext_vector_type(4)));

constexpr int kHW = 65536;           // 256*256
constexpr int kP  = 262144;          // 4 * kHW total pixels

__device__ __forceinline__ unsigned short f2bf(float x) {
  unsigned u = __builtin_bit_cast(unsigned, x);
  u += 0x7fffu + ((u >> 16) & 1u);
  return (unsigned short)(u >> 16);
}
__device__ __forceinline__ float bf2f(unsigned short h) {
  unsigned u = ((unsigned)h) << 16;
  return __builtin_bit_cast(float, u);
}
__device__ __forceinline__ void split2(float v, unsigned short& h, unsigned short& l) {
  unsigned short hh = f2bf(v);
  h = hh;
  l = f2bf(v - bf2f(hh));
}

// ---------------- bias table: bias_tab[h][i][j], h<6, i,j<64 ----------------
__global__ void bias_kernel(const float* __restrict__ w1, const float* __restrict__ b1,
                            const float* __restrict__ w2, const float* __restrict__ b2,
                            float* __restrict__ bias_tab) {
  int i = blockIdx.x;
  int j = threadIdx.x;
  float dy = (float)((i >> 3) - (j >> 3));
  float dx = (float)((i & 7) - (j & 7));
  float r0 = copysignf(log1pf(fabsf(dy)), dy);
  float r1 = copysignf(log1pf(fabsf(dx)), dx);
  float acc[6];
#pragma unroll
  for (int h = 0; h < 6; ++h) acc[h] = b2[h];
  for (int t = 0; t < 256; ++t) {
    float hv = fmaf(r0, w1[t], fmaf(r1, w1[256 + t], b1[t]));
    hv = fmaxf(hv, 0.f);
#pragma unroll
    for (int h = 0; h < 6; ++h) acc[h] = fmaf(hv, w2[t * 6 + h], acc[h]);
  }
#pragma unroll
  for (int h = 0; h < 6; ++h) bias_tab[h * 4096 + i * 64 + j] = acc[h];
}

// ---------------- weight prep: fp32 -> bf16 hi/lo planes ---------------------
__global__ void prep_weights(const float* __restrict__ qk_w, const float* __restrict__ v_w,
                             const float* __restrict__ c1w, const float* __restrict__ c2w,
                             const float* __restrict__ pjw,
                             unsigned short* __restrict__ Wqh, unsigned short* __restrict__ Wql,
                             unsigned short* __restrict__ W1h, unsigned short* __restrict__ W1l,
                             unsigned short* __restrict__ W2h, unsigned short* __restrict__ W2l,
                             unsigned short* __restrict__ Wph, unsigned short* __restrict__ Wpl) {
  int i = blockIdx.x * 256 + threadIdx.x;
  if (i < 27648) {
    float v = (i < 18432) ? qk_w[i] : v_w[i - 18432];
    split2(v, Wqh[i], Wql[i]);
  }
  if (i < 82944) {
    int dlt = i / 9216;
    int oc  = (i / 96) % 96;
    int ic  = i % 96;
    int src = (oc * 96 + ic) * 9 + dlt;
    split2(c1w[src], W1h[i], W1l[i]);
    split2(c2w[src], W2h[i], W2l[i]);
  }
  if (i < 9216) split2(pjw[i], Wph[i], Wpl[i]);
}

// ---------------- X: NCHW fp32 -> NHWC bf16 (hi only) -----------------------
__global__ __launch_bounds__(256) void split_x(const float* __restrict__ X,
                                               unsigned short* __restrict__ Xh) {
  __shared__ float tile[96][65];
  int t = threadIdx.x;
  size_t p0 = (size_t)blockIdx.x * 64;
  int b = (int)(p0 >> 16), pix = (int)(p0 & 65535);
  const float* xb = X + (size_t)b * 96 * kHW + pix;
#pragma unroll
  for (int i = 0; i < 24; ++i) {
    int ic = (t >> 6) + i * 4;
    tile[ic][t & 63] = xb[(size_t)ic * kHW + (t & 63)];
  }
  __syncthreads();
  int px = t >> 2;
  size_t outbase = (p0 + px) * 96;
#pragma unroll
  for (int cc = 0; cc < 3; ++cc) {
    int c = (t & 3) + cc * 4;
    us8 h8;
#pragma unroll
    for (int j = 0; j < 8; ++j) h8[j] = f2bf(tile[c * 8 + j][px]);
    *(us8*)(Xh + outbase + c * 8) = h8;
  }
}

// ---------------- merged QKV GEMM: X read once, B-frags in regs -------------
// z=0: Q*0.25 -> head-planar; z=1: K -> head-planar; z=2: V -> row [p][96]
__global__ __launch_bounds__(256, 2) void qkv_gemm(
    const unsigned short* __restrict__ Wqh, const unsigned short* __restrict__ Wql,
    const unsigned short* __restrict__ Xh,
    const float* __restrict__ qk_b, const float* __restrict__ v_b,
    unsigned short* __restrict__ Qp, unsigned short* __restrict__ Kp,
    unsigned short* __restrict__ Vr) {
  int t = threadIdx.x, wv = t >> 6, lane = t & 63;
  size_t px0 = (size_t)blockIdx.x * 256 + wv * 64;
  int col = lane & 15, g = lane >> 4;

  const char* bH = (const char*)Xh + ((px0 + col) * 96 + g * 8) * 2;
  short8 Bh[3][4];
#pragma unroll
  for (int ks = 0; ks < 3; ++ks)
#pragma unroll
    for (int nf = 0; nf < 4; ++nf)
      Bh[ks][nf] = *(const short8*)(bH + (size_t)(nf * 16 * 96 + ks * 32) * 2);

#pragma unroll 1
  for (int z = 0; z < 3; ++z) {
    f32x4 acc[6][4];
#pragma unroll
    for (int m = 0; m < 6; ++m)
#pragma unroll
      for (int n = 0; n < 4; ++n) acc[m][n] = (f32x4)0.f;
    const char* aH = (const char*)(Wqh + z * 9216) + (size_t)(col * 96 + g * 8) * 2;
    const char* aL = (const char*)(Wql + z * 9216) + (size_t)(col * 96 + g * 8) * 2;
#pragma unroll
    for (int ks = 0; ks < 3; ++ks) {
      short8 Ah[6], Al[6];
#pragma unroll
      for (int mf = 0; mf < 6; ++mf) {
        Ah[mf] = *(const short8*)(aH + (size_t)(mf * 16 * 96 + ks * 32) * 2);
        Al[mf] = *(const short8*)(aL + (size_t)(mf * 16 * 96 + ks * 32) * 2);
      }
#pragma unroll
      for (int mf = 0; mf < 6; ++mf)
#pragma unroll
        for (int nf = 0; nf < 4; ++nf) {
          acc[mf][nf] = __builtin_amdgcn_mfma_f32_16x16x32_bf16(Ah[mf], Bh[ks][nf], acc[mf][nf], 0, 0, 0);
          acc[mf][nf] = __builtin_amdgcn_mfma_f32_16x16x32_bf16(Al[mf], Bh[ks][nf], acc[mf][nf], 0, 0, 0);
        }
    }
    const float* bias = (z == 0) ? qk_b : (z == 1 ? qk_b + 96 : v_b);
    float scale = (z == 0) ? 0.25f : 1.f;
#pragma unroll
    for (int mf = 0; mf < 6; ++mf) {
      int oc0 = mf * 16 + g * 4;
      f32x4 bv;
#pragma unroll
      for (int r = 0; r < 4; ++r) bv[r] = bias[oc0 + r];
#pragma unroll
      for (int nf = 0; nf < 4; ++nf) {
        size_t p = px0 + nf * 16 + col;
        f32x4 v = (acc[mf][nf] + bv) * scale;
        us4 o;
#pragma unroll
        for (int r = 0; r < 4; ++r) o[r] = f2bf(v[r]);
        if (z == 0)      *(us4*)(Qp + ((size_t)mf * kP + p) * 16 + g * 4) = o;
        else if (z == 1) *(us4*)(Kp + ((size_t)mf * kP + p) * 16 + g * 4) = o;
        else             *(us4*)(Vr + p * 96 + oc0) = o;
      }
    }
  }
}

// ---------------- attention: Q/K head-planar, V from row buffer -------------
__global__ __launch_bounds__(256) void attn_kernel(
    const unsigned short* __restrict__ Qp, const unsigned short* __restrict__ Kp,
    const unsigned short* __restrict__ Vr, const float* __restrict__ bias_tab,
    float* __restrict__ out) {
  __shared__ float bs[64 * 65];
  __shared__ float4 kls[4][4][64];
  __shared__ float4 vls[4][4][64];
  int t = threadIdx.x;
  int wv = t >> 6, lane = t & 63;
  int h = blockIdx.y;
  int wid = blockIdx.x * 4 + wv;
  int b = wid >> 10, wy = (wid >> 5) & 31, wx = wid & 31;
  size_t p = ((size_t)b << 16) + (size_t)(wy * 8 + (lane >> 3)) * 256 + wx * 8 + (lane & 7);
  size_t base = ((size_t)h * kP + p) * 16;
  us8 q0 = *(const us8*)(Qp + base), q1 = *(const us8*)(Qp + base + 8);
  us8 k0 = *(const us8*)(Kp + base), k1 = *(const us8*)(Kp + base + 8);
  size_t vbase = p * 96 + h * 16;
  us8 v0 = *(const us8*)(Vr + vbase), v1 = *(const us8*)(Vr + vbase + 8);
  float q[16];
#pragma unroll
  for (int d = 0; d < 8; ++d) {
    q[d]     = bf2f(q0[d]);
    q[8 + d] = bf2f(q1[d]);
  }
  kls[wv][0][lane] = make_float4(bf2f(k0[0]), bf2f(k0[1]), bf2f(k0[2]), bf2f(k0[3]));
  kls[wv][1][lane] = make_float4(bf2f(k0[4]), bf2f(k0[5]), bf2f(k0[6]), bf2f(k0[7]));
  kls[wv][2][lane] = make_float4(bf2f(k1[0]), bf2f(k1[1]), bf2f(k1[2]), bf2f(k1[3]));
  kls[wv][3][lane] = make_float4(bf2f(k1[4]), bf2f(k1[5]), bf2f(k1[6]), bf2f(k1[7]));
  vls[wv][0][lane] = make_float4(bf2f(v0[0]), bf2f(v0[1]), bf2f(v0[2]), bf2f(v0[3]));
  vls[wv][1][lane] = make_float4(bf2f(v0[4]), bf2f(v0[5]), bf2f(v0[6]), bf2f(v0[7]));
  vls[wv][2][lane] = make_float4(bf2f(v1[0]), bf2f(v1[1]), bf2f(v1[2]), bf2f(v1[3]));
  vls[wv][3][lane] = make_float4(bf2f(v1[4]), bf2f(v1[5]), bf2f(v1[6]), bf2f(v1[7]));
  {
    const float* bp = bias_tab + h * 4096;
#pragma unroll
    for (int r0 = 0; r0 < 16; ++r0) {
      int r = wv * 16 + r0;
      bs[r * 65 + lane] = bp[r * 64 + lane];
    }
  }
  __syncthreads();

  const float* brow = bs + lane * 65;
  float s[64];
#pragma unroll
  for (int j = 0; j < 64; ++j) {
    float kk[16];
    *(float4*)&kk[0]  = kls[wv][0][j];
    *(float4*)&kk[4]  = kls[wv][1][j];
    *(float4*)&kk[8]  = kls[wv][2][j];
    *(float4*)&kk[12] = kls[wv][3][j];
    float dot = brow[j];
#pragma unroll
    for (int d = 0; d < 16; ++d) dot = fmaf(q[d], kk[d], dot);
    s[j] = dot;
  }
  float m = s[0];
#pragma unroll
  for (int j = 1; j < 64; ++j) m = fmaxf(m, s[j]);
  float sum = 0.f;
#pragma unroll
  for (int j = 0; j < 64; ++j) { s[j] = __expf(s[j] - m); sum += s[j]; }
  float r = 1.f / sum;
  float o[16];
#pragma unroll
  for (int d = 0; d < 16; ++d) o[d] = 0.f;
#pragma unroll
  for (int j = 0; j < 64; ++j) {
    float vv[16];
    *(float4*)&vv[0]  = vls[wv][0][j];
    *(float4*)&vv[4]  = vls[wv][1][j];
    *(float4*)&vv[8]  = vls[wv][2][j];
    *(float4*)&vv[12] = vls[wv][3][j];
    float pj = s[j];
#pragma unroll
    for (int d = 0; d < 16; ++d) o[d] = fmaf(pj, vv[d], o[d]);
  }
#pragma unroll
  for (int d = 0; d < 16; ++d) o[d] *= r;
  float* op = out + base;
  *(float4*)(op)      = *(float4*)&o[0];
  *(float4*)(op + 4)  = *(float4*)&o[4];
  *(float4*)(op + 8)  = *(float4*)&o[8];
  *(float4*)(op + 12) = *(float4*)&o[12];
}

// ---------------- conv: LDS-staged B, rolling row double-buffer -------------
// LDS row buffer layout: chunk(ks, g', pp) = ks*520 + g'*130 + pp  (16B chunks)
// g' = g ^ (pp&3).  Read chunk%8 = (2g'+pp)%8 covers all 8 bank groups per
// 16-lane quarter-wave (enumerated for g=0..3) -> conflict-free b128 reads.
constexpr int kRowB = 3 * 520 * 16;  // 24960 bytes per row buffer
constexpr int kChunks = 130 * 12;    // 1560 16-B chunks per row

__device__ __forceinline__ void stage_issue(const unsigned short* __restrict__ row,
                                            int x0, int t, us8 (&v)[7]) {
#pragma unroll
  for (int i = 0; i < 7; ++i) {
    int idx = i * 256 + t;
    if (idx < kChunks) {
      int pp = idx / 12, cb = idx % 12;
      int xx = x0 - 1 + pp;
      xx = xx < 0 ? 1 : (xx > 255 ? 254 : xx);
      v[i] = *(const us8*)(row + (size_t)xx * 96 + cb * 8);
    }
  }
}
__device__ __forceinline__ void stage_write(char* __restrict__ lds, int t, const us8 (&v)[7]) {
#pragma unroll
  for (int i = 0; i < 7; ++i) {
    int idx = i * 256 + t;
    if (idx < kChunks) {
      int pp = idx / 12, cb = idx % 12;
      int gq = cb & 3, ks = cb >> 2;
      int dst = ks * 8320 + ((gq ^ (pp & 3)) * 2080) + pp * 16;
      *(us8*)(lds + dst) = v[i];
    }
  }
}

__device__ __forceinline__ void conv_dy(
    const char* __restrict__ lds,
    const unsigned short* __restrict__ Wh, const unsigned short* __restrict__ Wl,
    int tap0, int och, int xq, int col, int g, f32x4 (&acc)[3][4]) {
#pragma unroll
  for (int dx = 0; dx < 3; ++dx) {
    const char* ah = (const char*)Wh + ((size_t)(tap0 + dx) * 9216 + och * 4608 + col * 96 + g * 8) * 2;
    const char* al = (const char*)Wl + ((size_t)(tap0 + dx) * 9216 + och * 4608 + col * 96 + g * 8) * 2;
    int ppb = xq * 64 + col + dx;
    const char* bp = lds + ((g ^ (ppb & 3)) * 2080 + ppb * 16);
#pragma unroll
    for (int ks = 0; ks < 3; ++ks) {
      short8 Ah[3], Al[3], Bf[4];
#pragma unroll
      for (int mf = 0; mf < 3; ++mf) {
        Ah[mf] = *(const short8*)(ah + (size_t)(mf * 16 * 96 + ks * 32) * 2);
        Al[mf] = *(const short8*)(al + (size_t)(mf * 16 * 96 + ks * 32) * 2);
      }
#pragma unroll
      for (int nf = 0; nf < 4; ++nf)
        Bf[nf] = *(const short8*)(bp + ks * 8320 + nf * 256);
#pragma unroll
      for (int mf = 0; mf < 3; ++mf)
#pragma unroll
        for (int nf = 0; nf < 4; ++nf) {
          acc[mf][nf] = __builtin_amdgcn_mfma_f32_16x16x32_bf16(Ah[mf], Bf[nf], acc[mf][nf], 0, 0, 0);
          acc[mf][nf] = __builtin_amdgcn_mfma_f32_16x16x32_bf16(Al[mf], Bf[nf], acc[mf][nf], 0, 0, 0);
        }
    }
  }
}

template <int MODE>
__global__ __launch_bounds__(256, 3) void conv_lds(
    const unsigned short* __restrict__ Wh, const unsigned short* __restrict__ Wl,
    const unsigned short* __restrict__ B_, const float* __restrict__ bias,
    const float* __restrict__ attn, unsigned short* __restrict__ O_) {
  __shared__ char lds[2][kRowB];
  int t = threadIdx.x, wv = t >> 6, lane = t & 63;
  int col = lane & 15, g = lane >> 4;
  int och = wv >> 1, xq = wv & 1;
  int bid = blockIdx.x;
  int g8 = (bid & 7) * 256 + (bid >> 3);   // XCD-chunked: consecutive rows per XCD
  int xh = g8 & 1;
  int ry = g8 >> 1;                        // 0..1023
  int b = ry >> 8, y = ry & 255;
  int x0 = xh * 128;

  int ym = (y == 0) ? 1 : y - 1;
  int yp = (y == 255) ? 254 : y + 1;
  const unsigned short* rowm = B_ + ((size_t)b * kHW + (size_t)ym * 256) * 96;
  const unsigned short* row0 = B_ + ((size_t)b * kHW + (size_t)y  * 256) * 96;
  const unsigned short* rowp = B_ + ((size_t)b * kHW + (size_t)yp * 256) * 96;

  f32x4 acc[3][4];
#pragma unroll
  for (int m = 0; m < 3; ++m)
#pragma unroll
    for (int n = 0; n < 4; ++n) acc[m][n] = (f32x4)0.f;

  us8 stg[7];
  // prologue: stage row y-1 into buf0
  stage_issue(rowm, x0, t, stg);
  stage_write(lds[0], t, stg);
  __syncthreads();

  // dy=0 on buf0 while staging row y into buf1
  stage_issue(row0, x0, t, stg);
  conv_dy(lds[0], Wh, Wl, 0, och, xq, col, g, acc);
  stage_write(lds[1], t, stg);
  __syncthreads();

  // dy=1 on buf1 while staging row y+1 into buf0
  stage_issue(rowp, x0, t, stg);
  conv_dy(lds[1], Wh, Wl, 3, och, xq, col, g, acc);
  stage_write(lds[0], t, stg);
  __syncthreads();

  // dy=2 on buf0
  conv_dy(lds[0], Wh, Wl, 6, och, xq, col, g, acc);

  size_t prow = (size_t)b * kHW + (size_t)y * 256;
#pragma unroll
  for (int mf = 0; mf < 3; ++mf) {
    int oc0 = och * 48 + mf * 16 + g * 4;
    f32x4 bv;
#pragma unroll
    for (int r = 0; r < 4; ++r) bv[r] = bias[oc0 + r];
#pragma unroll
    for (int nf = 0; nf < 4; ++nf) {
      size_t p = prow + x0 + xq * 64 + nf * 16 + col;
      f32x4 v = acc[mf][nf] + bv;
      if (MODE == 0) {
#pragma unroll
        for (int r = 0; r < 4; ++r) v[r] = fmaxf(v[r], 0.f);
      } else {
        float4 a = *(const float4*)(attn + ((size_t)(och * 3 + mf) * kP + p) * 16 + g * 4);
        v[0] += a.x; v[1] += a.y; v[2] += a.z; v[3] += a.w;
      }
      us4 o;
#pragma unroll
      for (int r = 0; r < 4; ++r) o[r] = f2bf(v[r]);
      *(us4*)(O_ + p * 96 + oc0) = o;
    }
  }
}

// ---------------- final projection -> d_out NCHW fp32 ------------------------
__global__ __launch_bounds__(256, 2) void proj_gemm(
    const unsigned short* __restrict__ Wph, const unsigned short* __restrict__ Wpl,
    const unsigned short* __restrict__ S_, const float* __restrict__ bias,
    float* __restrict__ out) {
  int t = threadIdx.x, wv = t >> 6, lane = t & 63;
  size_t px0 = (size_t)blockIdx.x * 256 + wv * 64;
  int col = lane & 15, g = lane >> 4;
  f32x4 acc[6][4];
#pragma unroll
  for (int m = 0; m < 6; ++m)
#pragma unroll
    for (int n = 0; n < 4; ++n) acc[m][n] = (f32x4)0.f;
  const char* aH = (const char*)Wph + (size_t)(col * 96 + g * 8) * 2;
  const char* aL = (const char*)Wpl + (size_t)(col * 96 + g * 8) * 2;
  const char* bH = (const char*)S_ + ((px0 + col) * 96 + g * 8) * 2;
#pragma unroll
  for (int ks = 0; ks < 3; ++ks) {
    short8 Ah[6], Al[6], Bf[4];
#pragma unroll
    for (int mf = 0; mf < 6; ++mf) {
      Ah[mf] = *(const short8*)(aH + (size_t)(mf * 16 * 96 + ks * 32) * 2);
      Al[mf] = *(const short8*)(aL + (size_t)(mf * 16 * 96 + ks * 32) * 2);
    }
#pragma unroll
    for (int nf = 0; nf < 4; ++nf)
      Bf[nf] = *(const short8*)(bH + (size_t)(nf * 16 * 96 + ks * 32) * 2);
#pragma unroll
    for (int mf = 0; mf < 6; ++mf)
#pragma unroll
      for (int nf = 0; nf < 4; ++nf) {
        acc[mf][nf] = __builtin_amdgcn_mfma_f32_16x16x32_bf16(Ah[mf], Bf[nf], acc[mf][nf], 0, 0, 0);
        acc[mf][nf] = __builtin_amdgcn_mfma_f32_16x16x32_bf16(Al[mf], Bf[nf], acc[mf][nf], 0, 0, 0);
      }
  }
#pragma unroll
  for (int mf = 0; mf < 6; ++mf) {
    int oc0 = mf * 16 + g * 4;
#pragma unroll
    for (int nf = 0; nf < 4; ++nf) {
      size_t p = px0 + nf * 16 + col;
      size_t bb = p >> 16, pix = p & 65535;
      f32x4 v = acc[mf][nf];
#pragma unroll
      for (int r = 0; r < 4; ++r)
        out[(bb * 96 + oc0 + r) * (size_t)kHW + pix] = v[r] + bias[oc0 + r];
    }
  }
}

extern "C" void kernel_launch(void* const* d_in, const int* in_sizes, int n_in,
                              void* d_out, int out_size, void* d_ws, size_t ws_size,
                              hipStream_t stream) {
  const float* X       = (const float*)d_in[0];
  const float* V_w     = (const float*)d_in[1];
  const float* V_b     = (const float*)d_in[2];
  const float* QK_w    = (const float*)d_in[3];
  const float* QK_b    = (const float*)d_in[4];
  const float* meta_w1 = (const float*)d_in[5];
  const float* meta_b1 = (const float*)d_in[6];
  const float* meta_w2 = (const float*)d_in[7];
  const float* meta_b2 = (const float*)d_in[8];
  const float* conv1_w = (const float*)d_in[9];
  const float* conv1_b = (const float*)d_in[10];
  const float* conv2_w = (const float*)d_in[11];
  const float* conv2_b = (const float*)d_in[12];
  const float* proj_w  = (const float*)d_in[13];
  const float* proj_b  = (const float*)d_in[14];
  float* out = (float*)d_out;

  char* w = (char*)d_ws;
  const size_t PLANE = (size_t)kP * 96 * 2;      // 50,331,648 B
  unsigned short* Xh = (unsigned short*)(w + 0 * PLANE);
  unsigned short* Qp = (unsigned short*)(w + 1 * PLANE);
  unsigned short* Kp = (unsigned short*)(w + 2 * PLANE);
  unsigned short* Vr = (unsigned short*)(w + 3 * PLANE);
  float* bias_tab    = (float*)(w + 4 * PLANE);
  unsigned short* Wqh = (unsigned short*)(w + 4 * PLANE + 98304);
  unsigned short* Wql = Wqh + 27648;
  unsigned short* W1h = Wql + 27648;
  unsigned short* W1l = W1h + 82944;
  unsigned short* W2h = W1l + 82944;
  unsigned short* W2l = W2h + 82944;
  unsigned short* Wph = W2l + 82944;
  unsigned short* Wpl = Wph + 9216;
  // stream-ordered aliases
  unsigned short* T1r = Xh;            // X dead after qkv_gemm
  unsigned short* S2r = Qp;            // Q dead after attn
  float* attnF = out;                  // d_out as head-planar f32 scratch; proj overwrites

  bias_kernel<<<dim3(64), dim3(64), 0, stream>>>(meta_w1, meta_b1, meta_w2, meta_b2, bias_tab);
  prep_weights<<<dim3(324), dim3(256), 0, stream>>>(QK_w, V_w, conv1_w, conv2_w, proj_w,
                                                    Wqh, Wql, W1h, W1l, W2h, W2l, Wph, Wpl);
  split_x<<<dim3(4096), dim3(256), 0, stream>>>(X, Xh);
  qkv_gemm<<<dim3(1024), dim3(256), 0, stream>>>(Wqh, Wql, Xh, QK_b, V_b, Qp, Kp, Vr);
  attn_kernel<<<dim3(1024, 6), dim3(256), 0, stream>>>(Qp, Kp, Vr, bias_tab, attnF);
  conv_lds<0><<<dim3(2048), dim3(256), 0, stream>>>(W1h, W1l, Vr, conv1_b, nullptr, T1r);
  conv_lds<1><<<dim3(2048), dim3(256), 0, stream>>>(W2h, W2l, T1r, conv2_b, attnF, S2r);
  proj_gemm<<<dim3(1024), dim3(256), 0, stream>>>(Wph, Wpl, S2r, proj_b, out);
}

// Round 8
// 548.369 us; speedup vs baseline: 1.4228x; 1.0322x over previous
//
#include <hip/hip_runtime.h>
#include <cmath>

typedef short  short8 __attribute__((ext_vector_type(8)));
typedef float  f32x4  __attribute__((ext_vector_type(4)));
typedef unsigned short us8 __attribute__((ext_vector_type(8)));
typedef unsigned short us4 __attribute__((ext_vector_type(4)));

constexpr int kHW = 65536;           // 256*256
constexpr int kP  = 262144;          // 4 * kHW total pixels

__device__ __forceinline__ unsigned short f2bf(float x) {
  unsigned u = __builtin_bit_cast(unsigned, x);
  u += 0x7fffu + ((u >> 16) & 1u);
  return (unsigned short)(u >> 16);
}
__device__ __forceinline__ float bf2f(unsigned short h) {
  unsigned u = ((unsigned)h) << 16;
  return __builtin_bit_cast(float, u);
}
__device__ __forceinline__ void split2(float v, unsigned short& h, unsigned short& l) {
  unsigned short hh = f2bf(v);
  h = hh;
  l = f2bf(v - bf2f(hh));
}

// ---------------- bias table: bias_tab[h][i][j], h<6, i,j<64 ----------------
__global__ void bias_kernel(const float* __restrict__ w1, const float* __restrict__ b1,
                            const float* __restrict__ w2, const float* __restrict__ b2,
                            float* __restrict__ bias_tab) {
  int i = blockIdx.x;
  int j = threadIdx.x;
  float dy = (float)((i >> 3) - (j >> 3));
  float dx = (float)((i & 7) - (j & 7));
  float r0 = copysignf(log1pf(fabsf(dy)), dy);
  float r1 = copysignf(log1pf(fabsf(dx)), dx);
  float acc[6];
#pragma unroll
  for (int h = 0; h < 6; ++h) acc[h] = b2[h];
  for (int t = 0; t < 256; ++t) {
    float hv = fmaf(r0, w1[t], fmaf(r1, w1[256 + t], b1[t]));
    hv = fmaxf(hv, 0.f);
#pragma unroll
    for (int h = 0; h < 6; ++h) acc[h] = fmaf(hv, w2[t * 6 + h], acc[h]);
  }
#pragma unroll
  for (int h = 0; h < 6; ++h) bias_tab[h * 4096 + i * 64 + j] = acc[h];
}

// ---------------- weight prep: fp32 -> bf16 hi/lo planes ---------------------
__global__ void prep_weights(const float* __restrict__ qk_w, const float* __restrict__ v_w,
                             const float* __restrict__ c1w, const float* __restrict__ c2w,
                             const float* __restrict__ pjw,
                             unsigned short* __restrict__ Wqh, unsigned short* __restrict__ Wql,
                             unsigned short* __restrict__ W1h,
                             unsigned short* __restrict__ W2h,
                             unsigned short* __restrict__ Wph, unsigned short* __restrict__ Wpl) {
  int i = blockIdx.x * 256 + threadIdx.x;
  if (i < 27648) {
    float v = (i < 18432) ? qk_w[i] : v_w[i - 18432];
    split2(v, Wqh[i], Wql[i]);
  }
  if (i < 82944) {
    int dlt = i / 9216;
    int oc  = (i / 96) % 96;
    int ic  = i % 96;
    int src = (oc * 96 + ic) * 9 + dlt;
    W1h[i] = f2bf(c1w[src]);
    W2h[i] = f2bf(c2w[src]);
  }
  if (i < 9216) split2(pjw[i], Wph[i], Wpl[i]);
}

// ---------------- X: NCHW fp32 -> NHWC bf16 (hi only) -----------------------
__global__ __launch_bounds__(256) void split_x(const float* __restrict__ X,
                                               unsigned short* __restrict__ Xh) {
  __shared__ float tile[96][65];
  int t = threadIdx.x;
  size_t p0 = (size_t)blockIdx.x * 64;
  int b = (int)(p0 >> 16), pix = (int)(p0 & 65535);
  const float* xb = X + (size_t)b * 96 * kHW + pix;
#pragma unroll
  for (int i = 0; i < 24; ++i) {
    int ic = (t >> 6) + i * 4;
    tile[ic][t & 63] = xb[(size_t)ic * kHW + (t & 63)];
  }
  __syncthreads();
  int px = t >> 2;
  size_t outbase = (p0 + px) * 96;
#pragma unroll
  for (int cc = 0; cc < 3; ++cc) {
    int c = (t & 3) + cc * 4;
    us8 h8;
#pragma unroll
    for (int j = 0; j < 8; ++j) h8[j] = f2bf(tile[c * 8 + j][px]);
    *(us8*)(Xh + outbase + c * 8) = h8;
  }
}

// ---------------- merged QKV GEMM: X read once, B-frags in regs -------------
// z=0: Q*0.25 -> head-planar; z=1: K -> head-planar; z=2: V -> row [p][96]
__global__ __launch_bounds__(256, 2) void qkv_gemm(
    const unsigned short* __restrict__ Wqh, const unsigned short* __restrict__ Wql,
    const unsigned short* __restrict__ Xh,
    const float* __restrict__ qk_b, const float* __restrict__ v_b,
    unsigned short* __restrict__ Qp, unsigned short* __restrict__ Kp,
    unsigned short* __restrict__ Vr) {
  int t = threadIdx.x, wv = t >> 6, lane = t & 63;
  size_t px0 = (size_t)blockIdx.x * 256 + wv * 64;
  int col = lane & 15, g = lane >> 4;

  const char* bH = (const char*)Xh + ((px0 + col) * 96 + g * 8) * 2;
  short8 Bh[3][4];
#pragma unroll
  for (int ks = 0; ks < 3; ++ks)
#pragma unroll
    for (int nf = 0; nf < 4; ++nf)
      Bh[ks][nf] = *(const short8*)(bH + (size_t)(nf * 16 * 96 + ks * 32) * 2);

#pragma unroll 1
  for (int z = 0; z < 3; ++z) {
    f32x4 acc[6][4];
#pragma unroll
    for (int m = 0; m < 6; ++m)
#pragma unroll
      for (int n = 0; n < 4; ++n) acc[m][n] = (f32x4)0.f;
    const char* aH = (const char*)(Wqh + z * 9216) + (size_t)(col * 96 + g * 8) * 2;
    const char* aL = (const char*)(Wql + z * 9216) + (size_t)(col * 96 + g * 8) * 2;
#pragma unroll
    for (int ks = 0; ks < 3; ++ks) {
      short8 Ah[6], Al[6];
#pragma unroll
      for (int mf = 0; mf < 6; ++mf) {
        Ah[mf] = *(const short8*)(aH + (size_t)(mf * 16 * 96 + ks * 32) * 2);
        Al[mf] = *(const short8*)(aL + (size_t)(mf * 16 * 96 + ks * 32) * 2);
      }
#pragma unroll
      for (int mf = 0; mf < 6; ++mf)
#pragma unroll
        for (int nf = 0; nf < 4; ++nf) {
          acc[mf][nf] = __builtin_amdgcn_mfma_f32_16x16x32_bf16(Ah[mf], Bh[ks][nf], acc[mf][nf], 0, 0, 0);
          acc[mf][nf] = __builtin_amdgcn_mfma_f32_16x16x32_bf16(Al[mf], Bh[ks][nf], acc[mf][nf], 0, 0, 0);
        }
    }
    const float* bias = (z == 0) ? qk_b : (z == 1 ? qk_b + 96 : v_b);
    float scale = (z == 0) ? 0.25f : 1.f;
#pragma unroll
    for (int mf = 0; mf < 6; ++mf) {
      int oc0 = mf * 16 + g * 4;
      f32x4 bv;
#pragma unroll
      for (int r = 0; r < 4; ++r) bv[r] = bias[oc0 + r];
#pragma unroll
      for (int nf = 0; nf < 4; ++nf) {
        size_t p = px0 + nf * 16 + col;
        f32x4 v = (acc[mf][nf] + bv) * scale;
        us4 o;
#pragma unroll
        for (int r = 0; r < 4; ++r) o[r] = f2bf(v[r]);
        if (z == 0)      *(us4*)(Qp + ((size_t)mf * kP + p) * 16 + g * 4) = o;
        else if (z == 1) *(us4*)(Kp + ((size_t)mf * kP + p) * 16 + g * 4) = o;
        else             *(us4*)(Vr + p * 96 + oc0) = o;
      }
    }
  }
}

// ---------------- attention: Q/K head-planar, V from row buffer -------------
__global__ __launch_bounds__(256) void attn_kernel(
    const unsigned short* __restrict__ Qp, const unsigned short* __restrict__ Kp,
    const unsigned short* __restrict__ Vr, const float* __restrict__ bias_tab,
    float* __restrict__ out) {
  __shared__ float bs[64 * 65];
  __shared__ float4 kls[4][4][64];
  __shared__ float4 vls[4][4][64];
  int t = threadIdx.x;
  int wv = t >> 6, lane = t & 63;
  int h = blockIdx.y;
  int wid = blockIdx.x * 4 + wv;
  int b = wid >> 10, wy = (wid >> 5) & 31, wx = wid & 31;
  size_t p = ((size_t)b << 16) + (size_t)(wy * 8 + (lane >> 3)) * 256 + wx * 8 + (lane & 7);
  size_t base = ((size_t)h * kP + p) * 16;
  us8 q0 = *(const us8*)(Qp + base), q1 = *(const us8*)(Qp + base + 8);
  us8 k0 = *(const us8*)(Kp + base), k1 = *(const us8*)(Kp + base + 8);
  size_t vbase = p * 96 + h * 16;
  us8 v0 = *(const us8*)(Vr + vbase), v1 = *(const us8*)(Vr + vbase + 8);
  float q[16];
#pragma unroll
  for (int d = 0; d < 8; ++d) {
    q[d]     = bf2f(q0[d]);
    q[8 + d] = bf2f(q1[d]);
  }
  kls[wv][0][lane] = make_float4(bf2f(k0[0]), bf2f(k0[1]), bf2f(k0[2]), bf2f(k0[3]));
  kls[wv][1][lane] = make_float4(bf2f(k0[4]), bf2f(k0[5]), bf2f(k0[6]), bf2f(k0[7]));
  kls[wv][2][lane] = make_float4(bf2f(k1[0]), bf2f(k1[1]), bf2f(k1[2]), bf2f(k1[3]));
  kls[wv][3][lane] = make_float4(bf2f(k1[4]), bf2f(k1[5]), bf2f(k1[6]), bf2f(k1[7]));
  vls[wv][0][lane] = make_float4(bf2f(v0[0]), bf2f(v0[1]), bf2f(v0[2]), bf2f(v0[3]));
  vls[wv][1][lane] = make_float4(bf2f(v0[4]), bf2f(v0[5]), bf2f(v0[6]), bf2f(v0[7]));
  vls[wv][2][lane] = make_float4(bf2f(v1[0]), bf2f(v1[1]), bf2f(v1[2]), bf2f(v1[3]));
  vls[wv][3][lane] = make_float4(bf2f(v1[4]), bf2f(v1[5]), bf2f(v1[6]), bf2f(v1[7]));
  {
    const float* bp = bias_tab + h * 4096;
#pragma unroll
    for (int r0 = 0; r0 < 16; ++r0) {
      int r = wv * 16 + r0;
      bs[r * 65 + lane] = bp[r * 64 + lane];
    }
  }
  __syncthreads();

  const float* brow = bs + lane * 65;
  float s[64];
#pragma unroll
  for (int j = 0; j < 64; ++j) {
    float kk[16];
    *(float4*)&kk[0]  = kls[wv][0][j];
    *(float4*)&kk[4]  = kls[wv][1][j];
    *(float4*)&kk[8]  = kls[wv][2][j];
    *(float4*)&kk[12] = kls[wv][3][j];
    float dot = brow[j];
#pragma unroll
    for (int d = 0; d < 16; ++d) dot = fmaf(q[d], kk[d], dot);
    s[j] = dot;
  }
  float m = s[0];
#pragma unroll
  for (int j = 1; j < 64; ++j) m = fmaxf(m, s[j]);
  float sum = 0.f;
#pragma unroll
  for (int j = 0; j < 64; ++j) { s[j] = __expf(s[j] - m); sum += s[j]; }
  float r = 1.f / sum;
  float o[16];
#pragma unroll
  for (int d = 0; d < 16; ++d) o[d] = 0.f;
#pragma unroll
  for (int j = 0; j < 64; ++j) {
    float vv[16];
    *(float4*)&vv[0]  = vls[wv][0][j];
    *(float4*)&vv[4]  = vls[wv][1][j];
    *(float4*)&vv[8]  = vls[wv][2][j];
    *(float4*)&vv[12] = vls[wv][3][j];
    float pj = s[j];
#pragma unroll
    for (int d = 0; d < 16; ++d) o[d] = fmaf(pj, vv[d], o[d]);
  }
#pragma unroll
  for (int d = 0; d < 16; ++d) o[d] *= r;
  float* op = out + base;
  *(float4*)(op)      = *(float4*)&o[0];
  *(float4*)(op + 4)  = *(float4*)&o[4];
  *(float4*)(op + 8)  = *(float4*)&o[8];
  *(float4*)(op + 12) = *(float4*)&o[12];
}

// ---------------- conv: LDS-staged B, single rolling row buffer --------------
// LDS row buffer: chunk(ks, g', pp) at ks*8320 + g'*2080 + pp*16, g' = g^(pp&3).
// 1-term weights (hi only): 27 A-loads + 36 LDS reads + 108 MFMA per dy.
constexpr int kRowB = 3 * 520 * 16;  // 24960 bytes
constexpr int kChunks = 130 * 12;    // 1560 16-B chunks per row

__device__ __forceinline__ void stage_issue(const unsigned short* __restrict__ row,
                                            int x0, int t, us8 (&v)[7]) {
#pragma unroll
  for (int i = 0; i < 7; ++i) {
    int idx = i * 256 + t;
    if (idx < kChunks) {
      int pp = idx / 12, cb = idx % 12;
      int xx = x0 - 1 + pp;
      xx = xx < 0 ? 1 : (xx > 255 ? 254 : xx);
      v[i] = *(const us8*)(row + (size_t)xx * 96 + cb * 8);
    }
  }
}
__device__ __forceinline__ void stage_write(char* __restrict__ lds, int t, const us8 (&v)[7]) {
#pragma unroll
  for (int i = 0; i < 7; ++i) {
    int idx = i * 256 + t;
    if (idx < kChunks) {
      int pp = idx / 12, cb = idx % 12;
      int gq = cb & 3, ks = cb >> 2;
      int dst = ks * 8320 + ((gq ^ (pp & 3)) * 2080) + pp * 16;
      *(us8*)(lds + dst) = v[i];
    }
  }
}

__device__ __forceinline__ void conv_dy(
    const char* __restrict__ lds, const unsigned short* __restrict__ Wh,
    int tap0, int och, int xq, int col, int g, f32x4 (&acc)[3][4]) {
#pragma unroll
  for (int dx = 0; dx < 3; ++dx) {
    const char* ah = (const char*)Wh + ((size_t)(tap0 + dx) * 9216 + och * 4608 + col * 96 + g * 8) * 2;
    int ppb = xq * 64 + col + dx;
    const char* bp = lds + ((g ^ (ppb & 3)) * 2080 + ppb * 16);
#pragma unroll
    for (int ks = 0; ks < 3; ++ks) {
      short8 Ah[3], Bf[4];
#pragma unroll
      for (int mf = 0; mf < 3; ++mf)
        Ah[mf] = *(const short8*)(ah + (size_t)(mf * 16 * 96 + ks * 32) * 2);
#pragma unroll
      for (int nf = 0; nf < 4; ++nf)
        Bf[nf] = *(const short8*)(bp + ks * 8320 + nf * 256);
#pragma unroll
      for (int mf = 0; mf < 3; ++mf)
#pragma unroll
        for (int nf = 0; nf < 4; ++nf)
          acc[mf][nf] = __builtin_amdgcn_mfma_f32_16x16x32_bf16(Ah[mf], Bf[nf], acc[mf][nf], 0, 0, 0);
    }
  }
}

template <int MODE>
__global__ __launch_bounds__(256, 4) void conv_lds(
    const unsigned short* __restrict__ Wh,
    const unsigned short* __restrict__ B_, const float* __restrict__ bias,
    const float* __restrict__ attn, unsigned short* __restrict__ O_) {
  __shared__ char lds[kRowB];
  int t = threadIdx.x, wv = t >> 6, lane = t & 63;
  int col = lane & 15, g = lane >> 4;
  int och = wv >> 1, xq = wv & 1;
  int bid = blockIdx.x;
  int g8 = (bid & 7) * 256 + (bid >> 3);   // XCD-chunked: consecutive rows per XCD
  int xh = g8 & 1;
  int ry = g8 >> 1;                        // 0..1023
  int b = ry >> 8, y = ry & 255;
  int x0 = xh * 128;

  int ym = (y == 0) ? 1 : y - 1;
  int yp = (y == 255) ? 254 : y + 1;
  const unsigned short* rowm = B_ + ((size_t)b * kHW + (size_t)ym * 256) * 96;
  const unsigned short* row0 = B_ + ((size_t)b * kHW + (size_t)y  * 256) * 96;
  const unsigned short* rowp = B_ + ((size_t)b * kHW + (size_t)yp * 256) * 96;

  f32x4 acc[3][4];
#pragma unroll
  for (int m = 0; m < 3; ++m)
#pragma unroll
    for (int n = 0; n < 4; ++n) acc[m][n] = (f32x4)0.f;

  us8 stg[7];
  // stage row y-1
  stage_issue(rowm, x0, t, stg);
  stage_write(lds, t, stg);
  __syncthreads();

  // dy=0 while loads of row y are in flight
  stage_issue(row0, x0, t, stg);
  conv_dy(lds, Wh, 0, och, xq, col, g, acc);
  __syncthreads();
  stage_write(lds, t, stg);
  __syncthreads();

  // dy=1 while loads of row y+1 are in flight
  stage_issue(rowp, x0, t, stg);
  conv_dy(lds, Wh, 3, och, xq, col, g, acc);
  __syncthreads();
  stage_write(lds, t, stg);
  __syncthreads();

  // dy=2
  conv_dy(lds, Wh, 6, och, xq, col, g, acc);

  size_t prow = (size_t)b * kHW + (size_t)y * 256;
#pragma unroll
  for (int mf = 0; mf < 3; ++mf) {
    int oc0 = och * 48 + mf * 16 + g * 4;
    f32x4 bv;
#pragma unroll
    for (int r = 0; r < 4; ++r) bv[r] = bias[oc0 + r];
#pragma unroll
    for (int nf = 0; nf < 4; ++nf) {
      size_t p = prow + x0 + xq * 64 + nf * 16 + col;
      f32x4 v = acc[mf][nf] + bv;
      if (MODE == 0) {
#pragma unroll
        for (int r = 0; r < 4; ++r) v[r] = fmaxf(v[r], 0.f);
      } else {
        float4 a = *(const float4*)(attn + ((size_t)(och * 3 + mf) * kP + p) * 16 + g * 4);
        v[0] += a.x; v[1] += a.y; v[2] += a.z; v[3] += a.w;
      }
      us4 o;
#pragma unroll
      for (int r = 0; r < 4; ++r) o[r] = f2bf(v[r]);
      *(us4*)(O_ + p * 96 + oc0) = o;
    }
  }
}

// ---------------- final projection -> d_out NCHW fp32 ------------------------
__global__ __launch_bounds__(256, 2) void proj_gemm(
    const unsigned short* __restrict__ Wph, const unsigned short* __restrict__ Wpl,
    const unsigned short* __restrict__ S_, const float* __restrict__ bias,
    float* __restrict__ out) {
  int t = threadIdx.x, wv = t >> 6, lane = t & 63;
  size_t px0 = (size_t)blockIdx.x * 256 + wv * 64;
  int col = lane & 15, g = lane >> 4;
  f32x4 acc[6][4];
#pragma unroll
  for (int m = 0; m < 6; ++m)
#pragma unroll
    for (int n = 0; n < 4; ++n) acc[m][n] = (f32x4)0.f;
  const char* aH = (const char*)Wph + (size_t)(col * 96 + g * 8) * 2;
  const char* aL = (const char*)Wpl + (size_t)(col * 96 + g * 8) * 2;
  const char* bH = (const char*)S_ + ((px0 + col) * 96 + g * 8) * 2;
#pragma unroll
  for (int ks = 0; ks < 3; ++ks) {
    short8 Ah[6], Al[6], Bf[4];
#pragma unroll
    for (int mf = 0; mf < 6; ++mf) {
      Ah[mf] = *(const short8*)(aH + (size_t)(mf * 16 * 96 + ks * 32) * 2);
      Al[mf] = *(const short8*)(aL + (size_t)(mf * 16 * 96 + ks * 32) * 2);
    }
#pragma unroll
    for (int nf = 0; nf < 4; ++nf)
      Bf[nf] = *(const short8*)(bH + (size_t)(nf * 16 * 96 + ks * 32) * 2);
#pragma unroll
    for (int mf = 0; mf < 6; ++mf)
#pragma unroll
      for (int nf = 0; nf < 4; ++nf) {
        acc[mf][nf] = __builtin_amdgcn_mfma_f32_16x16x32_bf16(Ah[mf], Bf[nf], acc[mf][nf], 0, 0, 0);
        acc[mf][nf] = __builtin_amdgcn_mfma_f32_16x16x32_bf16(Al[mf], Bf[nf], acc[mf][nf], 0, 0, 0);
      }
  }
#pragma unroll
  for (int mf = 0; mf < 6; ++mf) {
    int oc0 = mf * 16 + g * 4;
#pragma unroll
    for (int nf = 0; nf < 4; ++nf) {
      size_t p = px0 + nf * 16 + col;
      size_t bb = p >> 16, pix = p & 65535;
      f32x4 v = acc[mf][nf];
#pragma unroll
      for (int r = 0; r < 4; ++r)
        out[(bb * 96 + oc0 + r) * (size_t)kHW + pix] = v[r] + bias[oc0 + r];
    }
  }
}

extern "C" void kernel_launch(void* const* d_in, const int* in_sizes, int n_in,
                              void* d_out, int out_size, void* d_ws, size_t ws_size,
                              hipStream_t stream) {
  const float* X       = (const float*)d_in[0];
  const float* V_w     = (const float*)d_in[1];
  const float* V_b     = (const float*)d_in[2];
  const float* QK_w    = (const float*)d_in[3];
  const float* QK_b    = (const float*)d_in[4];
  const float* meta_w1 = (const float*)d_in[5];
  const float* meta_b1 = (const float*)d_in[6];
  const float* meta_w2 = (const float*)d_in[7];
  const float* meta_b2 = (const float*)d_in[8];
  const float* conv1_w = (const float*)d_in[9];
  const float* conv1_b = (const float*)d_in[10];
  const float* conv2_w = (const float*)d_in[11];
  const float* conv2_b = (const float*)d_in[12];
  const float* proj_w  = (const float*)d_in[13];
  const float* proj_b  = (const float*)d_in[14];
  float* out = (float*)d_out;

  char* w = (char*)d_ws;
  const size_t PLANE = (size_t)kP * 96 * 2;      // 50,331,648 B
  unsigned short* Xh = (unsigned short*)(w + 0 * PLANE);
  unsigned short* Qp = (unsigned short*)(w + 1 * PLANE);
  unsigned short* Kp = (unsigned short*)(w + 2 * PLANE);
  unsigned short* Vr = (unsigned short*)(w + 3 * PLANE);
  float* bias_tab    = (float*)(w + 4 * PLANE);
  unsigned short* Wqh = (unsigned short*)(w + 4 * PLANE + 98304);
  unsigned short* Wql = Wqh + 27648;
  unsigned short* W1h = Wql + 27648;
  unsigned short* W2h = W1h + 82944;
  unsigned short* Wph = W2h + 82944;
  unsigned short* Wpl = Wph + 9216;
  // stream-ordered aliases
  unsigned short* T1r = Xh;            // X dead after qkv_gemm
  unsigned short* S2r = Qp;            // Q dead after attn
  float* attnF = out;                  // d_out as head-planar f32 scratch; proj overwrites

  bias_kernel<<<dim3(64), dim3(64), 0, stream>>>(meta_w1, meta_b1, meta_w2, meta_b2, bias_tab);
  prep_weights<<<dim3(324), dim3(256), 0, stream>>>(QK_w, V_w, conv1_w, conv2_w, proj_w,
                                                    Wqh, Wql, W1h, W2h, Wph, Wpl);
  split_x<<<dim3(4096), dim3(256), 0, stream>>>(X, Xh);
  qkv_gemm<<<dim3(1024), dim3(256), 0, stream>>>(Wqh, Wql, Xh, QK_b, V_b, Qp, Kp, Vr);
  attn_kernel<<<dim3(1024, 6), dim3(256), 0, stream>>>(Qp, Kp, Vr, bias_tab, attnF);
  conv_lds<0><<<dim3(2048), dim3(256), 0, stream>>>(W1h, Vr, conv1_b, nullptr, T1r);
  conv_lds<1><<<dim3(2048), dim3(256), 0, stream>>>(W2h, T1r, conv2_b, attnF, S2r);
  proj_gemm<<<dim3(1024), dim3(256), 0, stream>>>(Wph, Wpl, S2r, proj_b, out);
}